// Round 1
// baseline (13584.993 us; speedup 1.0000x reference)
//
#include <hip/hip_runtime.h>
#include <hip/hip_cooperative_groups.h>

namespace cg = cooperative_groups;

typedef float f32x4 __attribute__((ext_vector_type(4)));
typedef __bf16 bf16x8 __attribute__((ext_vector_type(8)));

#define HDIM 2048
#define BATCH 256
#define TSTEPS 300
#define NBLK 256
#define NTHR 256

// ws layout (bytes)
#define WT_OFF 0u            // 2048*2048 bf16 = 8388608 B, MFMA B-frag order
#define RBUF_OFF 8388608u    // 2 * 256*2048 bf16 = 2097152 B (double buffer)
#define WI_OFF 10485760u     // 4*2048 f32 = 32768 B
#define WO_OFF 10518528u     // 2*2048 f32 = 16384 B  ([o][j] layout)

__device__ inline float tanh_fast(float x) {
  float e = __expf(2.0f * x);
  return 1.0f - 2.0f / (e + 1.0f);
}

__device__ inline unsigned short f2bf(float f) {
  union { float f; unsigned u; } v; v.f = f;
  unsigned r = v.u + 0x7fffu + ((v.u >> 16) & 1u);
  return (unsigned short)(r >> 16);
}

// Build wrec^T (= n m^T + rec_noise^T) in bf16, laid out in MFMA B-fragment order:
// elem index e = ((((jg*64 + kb)*2 + t16)*64) + lane)*8 + i
//   j = jg*32 + t16*16 + (lane&15)   (output column)
//   k = kb*32 + (lane>>4)*8 + i      (reduction index)
//   value = wrec[j][k] = rec_noise[j][k] + m[j][0]*n[k][0] + m[j][1]*n[k][1]
__global__ void prep_wt(const float* __restrict__ rec_noise,
                        const float* __restrict__ m, const float* __restrict__ n,
                        unsigned short* __restrict__ WT) {
  int base = (blockIdx.x * 256 + threadIdx.x) * 4;
#pragma unroll
  for (int ii = 0; ii < 4; ++ii) {
    int e = base + ii;
    int i = e & 7;
    int lane = (e >> 3) & 63;
    int t16 = (e >> 9) & 1;
    int kb = (e >> 10) & 63;
    int jg = e >> 16;
    int j = jg * 32 + t16 * 16 + (lane & 15);
    int k = kb * 32 + (lane >> 4) * 8 + i;
    float v = rec_noise[(size_t)j * HDIM + k] + m[j * 2] * n[k * 2] + m[j * 2 + 1] * n[k * 2 + 1];
    WT[e] = f2bf(v);
  }
}

// wi_full (f32 [4][2048]), wo_full (f32 [2][2048], transposed), r0 = tanh(h0) broadcast (bf16 [256][2048])
__global__ void prep_small(const float* __restrict__ wi, const float* __restrict__ si,
                           const float* __restrict__ wo, const float* __restrict__ so,
                           const float* __restrict__ h0,
                           float* __restrict__ wi_full, float* __restrict__ wo_full,
                           unsigned short* __restrict__ r0) {
  int idx = blockIdx.x * 256 + threadIdx.x;
  if (idx < BATCH * HDIM) {
    int j = idx & (HDIM - 1);
    r0[idx] = f2bf(tanh_fast(h0[j]));
  }
  if (idx < 4 * HDIM) wi_full[idx] = wi[idx] * si[idx >> 11];
  if (idx < 2 * HDIM) {
    int o = idx >> 11, j = idx & (HDIM - 1);
    wo_full[idx] = wo[j * 2 + o] * so[o];
  }
}

__global__ __launch_bounds__(NTHR) void rnn_run(
    const float* __restrict__ inp, const float* __restrict__ noise,
    const unsigned short* __restrict__ WT, unsigned short* __restrict__ rbuf,
    const float* __restrict__ wi_full, const float* __restrict__ wo_full,
    const float* __restrict__ h0, float* __restrict__ out) {
  extern __shared__ unsigned short Wlds[];  // 65536 bf16 = 128 KB: this block's W slice
  cg::grid_group grid = cg::this_grid();

  const int tid = threadIdx.x;
  const int l = tid & 63, w = tid >> 6;
  const int bid = blockIdx.x;
  const int mg = bid >> 6, jg = bid & 63;   // mg: 64-row tile of batch; jg: 32-col tile of H
  const int lr = l & 15, hi = l >> 4;
  const int b0w = mg * 64 + w * 16;         // this wave's 16 batch rows
  const int col0 = jg * 32 + lr;            // C-layout column for tile 0 (tile 1 = +16)

  // one-time: W slice global -> LDS (frag order, linear copy)
  {
    const f32x4* src = (const f32x4*)(WT + (size_t)jg * 65536);
    f32x4* dst = (f32x4*)Wlds;
    for (int u = tid; u < 8192; u += NTHR) dst[u] = src[u];
  }
  // h in registers, MFMA C layout: h[t16][q] = h[b0w+hi*4+q][col0+t16*16]
  float h[2][4];
  {
    float a0 = h0[col0], a1 = h0[col0 + 16];
#pragma unroll
    for (int q = 0; q < 4; ++q) { h[0][q] = a0; h[1][q] = a1; }
  }
  float wic[4][2];
#pragma unroll
  for (int i = 0; i < 4; ++i) {
    wic[i][0] = wi_full[i * HDIM + col0];
    wic[i][1] = wi_full[i * HDIM + col0 + 16];
  }
  __syncthreads();

  for (int t = 0; t <= TSTEPS; ++t) {
    const unsigned short* rr = rbuf + (size_t)(t & 1) * (BATCH * HDIM);
    unsigned short* rw = rbuf + (size_t)((t + 1) & 1) * (BATCH * HDIM);

    // ---- out_{t-1} = r_t @ wo_full : this block contributes k-slice [jg*32, jg*32+32) ----
    if (t >= 1) {
      const int k0 = jg * 32 + hi * 8;
      bf16x8 a = *(const bf16x8*)(rr + (size_t)(b0w + lr) * HDIM + k0);
      f32x4 w0a = *(const f32x4*)(wo_full + k0);
      f32x4 w0b = *(const f32x4*)(wo_full + k0 + 4);
      f32x4 w1a = *(const f32x4*)(wo_full + HDIM + k0);
      f32x4 w1b = *(const f32x4*)(wo_full + HDIM + k0 + 4);
      float o0 = 0.f, o1 = 0.f;
#pragma unroll
      for (int i = 0; i < 4; ++i) {
        float af = (float)a[i];
        o0 += af * w0a[i]; o1 += af * w1a[i];
      }
#pragma unroll
      for (int i = 0; i < 4; ++i) {
        float af = (float)a[i + 4];
        o0 += af * w0b[i]; o1 += af * w1b[i];
      }
      o0 += __shfl_xor(o0, 16, 64); o0 += __shfl_xor(o0, 32, 64);
      o1 += __shfl_xor(o1, 16, 64); o1 += __shfl_xor(o1, 32, 64);
      if (l < 16) {
        float* op = out + (size_t)(b0w + l) * (TSTEPS * 2) + (size_t)(t - 1) * 2;
        atomicAdd(op, o0);
        atomicAdd(op + 1, o1);
      }
    }
    if (t == TSTEPS) break;

    // ---- prefetch noise + input for this step (consumed after GEMM) ----
    float nz[2][4]; float4 xv[4];
#pragma unroll
    for (int q = 0; q < 4; ++q) {
      const int brow = b0w + hi * 4 + q;
      const float* np = noise + ((size_t)brow * TSTEPS + t) * HDIM;
      nz[0][q] = np[col0];
      nz[1][q] = np[col0 + 16];
      xv[q] = *(const float4*)(inp + ((size_t)brow * TSTEPS + t) * 4);
    }

    // ---- rec = r_t @ wrec.T for this block's 64x32 tile ----
    f32x4 acc0 = {0.f, 0.f, 0.f, 0.f}, acc1 = {0.f, 0.f, 0.f, 0.f};
    const unsigned short* abase = rr + (size_t)(b0w + lr) * HDIM + hi * 8;
    const bf16x8* Ws = (const bf16x8*)Wlds;
#pragma unroll 4
    for (int kb = 0; kb < 64; ++kb) {
      bf16x8 a = *(const bf16x8*)(abase + kb * 32);
      bf16x8 bA = Ws[(kb * 2 + 0) * 64 + l];
      bf16x8 bB = Ws[(kb * 2 + 1) * 64 + l];
      acc0 = __builtin_amdgcn_mfma_f32_16x16x32_bf16(a, bA, acc0, 0, 0, 0);
      acc1 = __builtin_amdgcn_mfma_f32_16x16x32_bf16(a, bB, acc1, 0, 0, 0);
    }

    // ---- h update + write r_{t+1} (bf16) ----
#pragma unroll
    for (int q = 0; q < 4; ++q) {
      float x0 = xv[q].x * wic[0][0] + xv[q].y * wic[1][0] + xv[q].z * wic[2][0] + xv[q].w * wic[3][0];
      float x1 = xv[q].x * wic[0][1] + xv[q].y * wic[1][1] + xv[q].z * wic[2][1] + xv[q].w * wic[3][1];
      float h0n = 0.8f * h[0][q] + 0.05f * nz[0][q] + 0.2f * (acc0[q] + x0);
      float h1n = 0.8f * h[1][q] + 0.05f * nz[1][q] + 0.2f * (acc1[q] + x1);
      h[0][q] = h0n; h[1][q] = h1n;
      const int brow = b0w + hi * 4 + q;
      unsigned short* rp = rw + (size_t)brow * HDIM;
      rp[col0] = f2bf(tanh_fast(h0n));
      rp[col0 + 16] = f2bf(tanh_fast(h1n));
    }

    grid.sync();
  }
}

extern "C" void kernel_launch(void* const* d_in, const int* in_sizes, int n_in,
                              void* d_out, int out_size, void* d_ws, size_t ws_size,
                              hipStream_t stream) {
  const float* inp = (const float*)d_in[0];
  const float* noise = (const float*)d_in[1];
  const float* wi = (const float*)d_in[2];
  const float* si = (const float*)d_in[3];
  const float* m = (const float*)d_in[4];
  const float* n = (const float*)d_in[5];
  const float* rec_noise = (const float*)d_in[6];
  const float* wo = (const float*)d_in[7];
  const float* so = (const float*)d_in[8];
  const float* h0 = (const float*)d_in[9];

  char* ws = (char*)d_ws;
  unsigned short* WT = (unsigned short*)(ws + WT_OFF);
  unsigned short* rbuf = (unsigned short*)(ws + RBUF_OFF);
  float* wi_full = (float*)(ws + WI_OFF);
  float* wo_full = (float*)(ws + WO_OFF);
  float* outp = (float*)d_out;

  // rebuild proxy params every call (ws is poisoned before timing)
  prep_wt<<<4096, 256, 0, stream>>>(rec_noise, m, n, WT);
  prep_small<<<2048, 256, 0, stream>>>(wi, si, wo, so, h0, wi_full, wo_full, rbuf);
  hipMemsetAsync(d_out, 0, (size_t)out_size * sizeof(float), stream);

  hipFuncSetAttribute((const void*)rnn_run, hipFuncAttributeMaxDynamicSharedMemorySize, 131072);
  const unsigned short* WTc = WT;
  void* kargs[8] = {(void*)&inp, (void*)&noise, (void*)&WTc, (void*)&rbuf,
                    (void*)&wi_full, (void*)&wo_full, (void*)&h0, (void*)&outp};
  hipLaunchCooperativeKernel((void*)rnn_run, dim3(NBLK), dim3(NTHR), kargs, 131072, stream);
}

// Round 2
// 6526.868 us; speedup vs baseline: 2.0814x; 2.0814x over previous
//
#include <hip/hip_runtime.h>

typedef float f32x4 __attribute__((ext_vector_type(4)));
typedef __bf16 bf16x8 __attribute__((ext_vector_type(8)));

#define HDIM 2048
#define BATCH 256
#define TSTEPS 300
#define NBLK 256
#define NTHR 256

// ws layout (bytes)
#define WT_OFF 0u            // 2048*2048 bf16 = 8388608 B, MFMA B-frag order
#define RBUF_OFF 8388608u    // 2 * 256*2048 bf16 = 2097152 B (double buffer)
#define WI_OFF 10485760u     // 4*2048 f32 = 32768 B
#define WO_OFF 10518528u     // 2*2048 f32 = 16384 B  ([o][j] layout)
#define BAR_OFF 10534912u    // 2 u32: arrive counter, generation

__device__ inline float tanh_fast(float x) {
  float e = __expf(2.0f * x);
  return 1.0f - 2.0f / (e + 1.0f);
}

__device__ inline unsigned short f2bf(float f) {
  union { float f; unsigned u; } v; v.f = f;
  unsigned r = v.u + 0x7fffu + ((v.u >> 16) & 1u);
  return (unsigned short)(r >> 16);
}

// Build wrec^T in bf16, MFMA B-frag order (unchanged from verified round-1 kernel)
__global__ void prep_wt(const float* __restrict__ rec_noise,
                        const float* __restrict__ m, const float* __restrict__ n,
                        unsigned short* __restrict__ WT) {
  int base = (blockIdx.x * 256 + threadIdx.x) * 4;
#pragma unroll
  for (int ii = 0; ii < 4; ++ii) {
    int e = base + ii;
    int i = e & 7;
    int lane = (e >> 3) & 63;
    int t16 = (e >> 9) & 1;
    int kb = (e >> 10) & 63;
    int jg = e >> 16;
    int j = jg * 32 + t16 * 16 + (lane & 15);
    int k = kb * 32 + (lane >> 4) * 8 + i;
    float v = rec_noise[(size_t)j * HDIM + k] + m[j * 2] * n[k * 2] + m[j * 2 + 1] * n[k * 2 + 1];
    WT[e] = f2bf(v);
  }
}

__global__ void prep_small(const float* __restrict__ wi, const float* __restrict__ si,
                           const float* __restrict__ wo, const float* __restrict__ so,
                           const float* __restrict__ h0,
                           float* __restrict__ wi_full, float* __restrict__ wo_full,
                           unsigned short* __restrict__ r0) {
  int idx = blockIdx.x * 256 + threadIdx.x;
  if (idx < BATCH * HDIM) {
    int j = idx & (HDIM - 1);
    r0[idx] = f2bf(tanh_fast(h0[j]));
  }
  if (idx < 4 * HDIM) wi_full[idx] = wi[idx] * si[idx >> 11];
  if (idx < 2 * HDIM) {
    int o = idx >> 11, j = idx & (HDIM - 1);
    wo_full[idx] = wo[j * 2 + o] * so[o];
  }
}

__global__ __launch_bounds__(NTHR, 1) void rnn_run(
    const float* __restrict__ inp, const float* __restrict__ noise,
    const unsigned short* __restrict__ WT, unsigned short* __restrict__ rbuf,
    const float* __restrict__ wi_full, const float* __restrict__ wo_full,
    const float* __restrict__ h0, float* __restrict__ out,
    unsigned* __restrict__ bar) {
  extern __shared__ unsigned short Wlds[];  // 128 KB: this block's W slice

  const int tid = threadIdx.x;
  const int l = tid & 63, w = tid >> 6;
  const int bid = blockIdx.x;
  const int mg = bid >> 6, jg = bid & 63;
  const int lr = l & 15, hi = l >> 4;
  const int b0w = mg * 64 + w * 16;
  const int col0 = jg * 32 + lr;
  const int k0 = jg * 32 + hi * 8;

  unsigned* cnt = bar;
  unsigned* gen = bar + 1;

  // one-time: W slice global -> LDS
  {
    const f32x4* src = (const f32x4*)(WT + (size_t)jg * 65536);
    f32x4* dst = (f32x4*)Wlds;
    for (int u = tid; u < 8192; u += NTHR) dst[u] = src[u];
  }
  // h in registers, MFMA C layout
  float h[2][4];
  {
    float a0 = h0[col0], a1 = h0[col0 + 16];
#pragma unroll
    for (int q = 0; q < 4; ++q) { h[0][q] = a0; h[1][q] = a1; }
  }
  float wic[4][2];
#pragma unroll
  for (int i = 0; i < 4; ++i) {
    wic[i][0] = wi_full[i * HDIM + col0];
    wic[i][1] = wi_full[i * HDIM + col0 + 16];
  }
  // hoist wo slice for the epilogue
  float woc0[8], woc1[8];
#pragma unroll
  for (int i = 0; i < 8; ++i) {
    woc0[i] = wo_full[k0 + i];
    woc1[i] = wo_full[HDIM + k0 + i];
  }
  __syncthreads();

  // prefetch t=0 noise + input
  float nz[2][4]; float4 xv[4];
#pragma unroll
  for (int q = 0; q < 4; ++q) {
    const int brow = b0w + hi * 4 + q;
    const float* np = noise + ((size_t)brow * TSTEPS + 0) * HDIM;
    nz[0][q] = np[col0];
    nz[1][q] = np[col0 + 16];
    xv[q] = *(const float4*)(inp + ((size_t)brow * TSTEPS + 0) * 4);
  }

  for (int t = 0; t < TSTEPS; ++t) {
    const unsigned short* rr = rbuf + (size_t)(t & 1) * (BATCH * HDIM);
    unsigned short* rw = rbuf + (size_t)((t + 1) & 1) * (BATCH * HDIM);

    // ---- rec = r_t @ wrec.T, 16-deep register-ring A pipeline ----
    const bf16x8* ap = (const bf16x8*)(rr + (size_t)(b0w + lr) * HDIM + hi * 8); // kb stride = 4 (x16B)
    bf16x8 ar[16];
#pragma unroll
    for (int i = 0; i < 16; ++i) ar[i] = ap[i * 4];
    f32x4 acc0 = {0.f, 0.f, 0.f, 0.f}, acc1 = {0.f, 0.f, 0.f, 0.f};
    const bf16x8* Ws = (const bf16x8*)Wlds;
#pragma unroll
    for (int kb = 0; kb < 64; ++kb) {
      bf16x8 a = ar[kb & 15];
      bf16x8 bA = Ws[(kb * 2 + 0) * 64 + l];
      bf16x8 bB = Ws[(kb * 2 + 1) * 64 + l];
      acc0 = __builtin_amdgcn_mfma_f32_16x16x32_bf16(a, bA, acc0, 0, 0, 0);
      acc1 = __builtin_amdgcn_mfma_f32_16x16x32_bf16(a, bB, acc1, 0, 0, 0);
      if (kb < 48) ar[kb & 15] = ap[(kb + 16) * 4];
    }

    // ---- h update + write r_{t+1} ----
#pragma unroll
    for (int q = 0; q < 4; ++q) {
      float x0 = xv[q].x * wic[0][0] + xv[q].y * wic[1][0] + xv[q].z * wic[2][0] + xv[q].w * wic[3][0];
      float x1 = xv[q].x * wic[0][1] + xv[q].y * wic[1][1] + xv[q].z * wic[2][1] + xv[q].w * wic[3][1];
      float h0n = 0.8f * h[0][q] + 0.05f * nz[0][q] + 0.2f * (acc0[q] + x0);
      float h1n = 0.8f * h[1][q] + 0.05f * nz[1][q] + 0.2f * (acc1[q] + x1);
      h[0][q] = h0n; h[1][q] = h1n;
      const int brow = b0w + hi * 4 + q;
      unsigned short* rp = rw + (size_t)brow * HDIM;
      rp[col0] = f2bf(tanh_fast(h0n));
      rp[col0 + 16] = f2bf(tanh_fast(h1n));
    }

    // ---- barrier arrive (release) ----
    __syncthreads();  // drains each wave's r stores (vmcnt) + block-level order
    if (tid == 0) {
      __builtin_amdgcn_fence(__ATOMIC_RELEASE, "agent");
      unsigned ticket = __hip_atomic_fetch_add(cnt, 1u, __ATOMIC_RELAXED, __HIP_MEMORY_SCOPE_AGENT);
      if (ticket == NBLK - 1) {
        __hip_atomic_store(cnt, 0u, __ATOMIC_RELAXED, __HIP_MEMORY_SCOPE_AGENT);
        __hip_atomic_store(gen, (unsigned)(t + 1), __ATOMIC_RELAXED, __HIP_MEMORY_SCOPE_AGENT);
      }
    }

    // ---- hidden under barrier: out_t = r_{t+1} @ wo (self rows x self k-slice) ----
    {
      bf16x8 a = *(const bf16x8*)(rw + (size_t)(b0w + lr) * HDIM + k0);
      float o0 = 0.f, o1 = 0.f;
#pragma unroll
      for (int i = 0; i < 8; ++i) {
        float af = (float)a[i];
        o0 += af * woc0[i];
        o1 += af * woc1[i];
      }
      o0 += __shfl_xor(o0, 16, 64); o0 += __shfl_xor(o0, 32, 64);
      o1 += __shfl_xor(o1, 16, 64); o1 += __shfl_xor(o1, 32, 64);
      if (l < 16) {
        float* op = out + (size_t)(b0w + l) * (TSTEPS * 2) + (size_t)t * 2;
        atomicAdd(op, o0);
        atomicAdd(op + 1, o1);
      }
    }

    if (t + 1 < TSTEPS) {
      // ---- hidden under barrier: prefetch t+1 noise + input ----
#pragma unroll
      for (int q = 0; q < 4; ++q) {
        const int brow = b0w + hi * 4 + q;
        const float* np = noise + ((size_t)brow * TSTEPS + (t + 1)) * HDIM;
        nz[0][q] = np[col0];
        nz[1][q] = np[col0 + 16];
        xv[q] = *(const float4*)(inp + ((size_t)brow * TSTEPS + (t + 1)) * 4);
      }
      // ---- barrier wait (acquire) ----
      if (tid == 0) {
        while (__hip_atomic_load(gen, __ATOMIC_RELAXED, __HIP_MEMORY_SCOPE_AGENT) < (unsigned)(t + 1))
          __builtin_amdgcn_s_sleep(1);
        __builtin_amdgcn_fence(__ATOMIC_ACQUIRE, "agent");
      }
      __syncthreads();
    }
  }
}

extern "C" void kernel_launch(void* const* d_in, const int* in_sizes, int n_in,
                              void* d_out, int out_size, void* d_ws, size_t ws_size,
                              hipStream_t stream) {
  const float* inp = (const float*)d_in[0];
  const float* noise = (const float*)d_in[1];
  const float* wi = (const float*)d_in[2];
  const float* si = (const float*)d_in[3];
  const float* m = (const float*)d_in[4];
  const float* n = (const float*)d_in[5];
  const float* rec_noise = (const float*)d_in[6];
  const float* wo = (const float*)d_in[7];
  const float* so = (const float*)d_in[8];
  const float* h0 = (const float*)d_in[9];

  char* ws = (char*)d_ws;
  unsigned short* WT = (unsigned short*)(ws + WT_OFF);
  unsigned short* rbuf = (unsigned short*)(ws + RBUF_OFF);
  float* wi_full = (float*)(ws + WI_OFF);
  float* wo_full = (float*)(ws + WO_OFF);
  unsigned* bar = (unsigned*)(ws + BAR_OFF);
  float* outp = (float*)d_out;

  // rebuild proxy params every call (ws is poisoned before timing)
  prep_wt<<<4096, 256, 0, stream>>>(rec_noise, m, n, WT);
  prep_small<<<2048, 256, 0, stream>>>(wi, si, wo, so, h0, wi_full, wo_full, rbuf);
  hipMemsetAsync(d_out, 0, (size_t)out_size * sizeof(float), stream);
  hipMemsetAsync(bar, 0, 2 * sizeof(unsigned), stream);

  hipFuncSetAttribute((const void*)rnn_run, hipFuncAttributeMaxDynamicSharedMemorySize, 131072);
  const unsigned short* WTc = WT;
  void* kargs[9] = {(void*)&inp, (void*)&noise, (void*)&WTc, (void*)&rbuf,
                    (void*)&wi_full, (void*)&wo_full, (void*)&h0, (void*)&outp,
                    (void*)&bar};
  hipLaunchCooperativeKernel((void*)rnn_run, dim3(NBLK), dim3(NTHR), kargs, 131072, stream);
}

// Round 4
// 4039.766 us; speedup vs baseline: 3.3628x; 1.6157x over previous
//
#include <hip/hip_runtime.h>

typedef float f32x4 __attribute__((ext_vector_type(4)));
typedef __bf16 bf16x8 __attribute__((ext_vector_type(8)));

#define HDIM 2048
#define BATCH 256
#define TSTEPS 300
#define NBLK 256
#define NTHR 256

// ws layout (bytes)
#define WT_OFF 0u            // 2048*2048 bf16 = 8388608 B, MFMA B-frag order
#define RBUF_OFF 8388608u    // 2 * 256*2048 bf16 = 2097152 B (double buffer)
#define WI_OFF 10485760u     // 4*2048 f32 = 32768 B
#define WO_OFF 10518528u     // 2*2048 f32 = 16384 B  ([o][j] layout)
#define BAR_OFF 10534912u    // 4 KB barrier area (u32 indices below)

// barrier area u32 indices
#define BX_CNT(x) ((x) * 32)          // per-XCD arrive counters (128B apart)
#define BX_RDY(x) (256 + (x) * 32)    // per-XCD ready generation
#define B_GCNT 512                    // global leader counter
#define B_GEN 544                     // step generation
#define B_GCNT0 576                   // init barrier counter
#define B_XTOT(x) (608 + (x))         // per-XCD block totals

#define AGENT __HIP_MEMORY_SCOPE_AGENT

__device__ inline float tanh_fast(float x) {
  float e = __expf(2.0f * x);
  return 1.0f - 2.0f / (e + 1.0f);
}

__device__ inline unsigned short f2bf(float f) {
  union { float f; unsigned u; } v; v.f = f;
  unsigned r = v.u + 0x7fffu + ((v.u >> 16) & 1u);
  return (unsigned short)(r >> 16);
}

// Build wrec^T in bf16, MFMA B-frag order (verified rounds 1-2)
__global__ void prep_wt(const float* __restrict__ rec_noise,
                        const float* __restrict__ m, const float* __restrict__ n,
                        unsigned short* __restrict__ WT) {
  int base = (blockIdx.x * 256 + threadIdx.x) * 4;
#pragma unroll
  for (int ii = 0; ii < 4; ++ii) {
    int e = base + ii;
    int i = e & 7;
    int lane = (e >> 3) & 63;
    int t16 = (e >> 9) & 1;
    int kb = (e >> 10) & 63;
    int jg = e >> 16;
    int j = jg * 32 + t16 * 16 + (lane & 15);
    int k = kb * 32 + (lane >> 4) * 8 + i;
    float v = rec_noise[(size_t)j * HDIM + k] + m[j * 2] * n[k * 2] + m[j * 2 + 1] * n[k * 2 + 1];
    WT[e] = f2bf(v);
  }
}

__global__ void prep_small(const float* __restrict__ wi, const float* __restrict__ si,
                           const float* __restrict__ wo, const float* __restrict__ so,
                           const float* __restrict__ h0,
                           float* __restrict__ wi_full, float* __restrict__ wo_full,
                           unsigned short* __restrict__ r0) {
  int idx = blockIdx.x * 256 + threadIdx.x;
  if (idx < BATCH * HDIM) {
    int j = idx & (HDIM - 1);
    r0[idx] = f2bf(tanh_fast(h0[j]));
  }
  if (idx < 4 * HDIM) wi_full[idx] = wi[idx] * si[idx >> 11];
  if (idx < 2 * HDIM) {
    int o = idx >> 11, j = idx & (HDIM - 1);
    wo_full[idx] = wo[j * 2 + o] * so[o];
  }
}

__global__ __launch_bounds__(NTHR, 1) void rnn_run(
    const float* __restrict__ inp, const float* __restrict__ noise,
    const unsigned short* __restrict__ WT, unsigned short* __restrict__ rbuf,
    const float* __restrict__ wi_full, const float* __restrict__ wo_full,
    const float* __restrict__ h0, float* __restrict__ out,
    unsigned* __restrict__ bar) {
  extern __shared__ unsigned short Wlds[];  // 128 KB: this block's W slice

  const int tid = threadIdx.x;
  const int l = tid & 63, w = tid >> 6;
  const int bid = blockIdx.x;
  const int mg = bid >> 6, jg = bid & 63;
  const int lr = l & 15, hi = l >> 4;
  const int b0w = mg * 64 + w * 16;
  const int col0 = jg * 32 + lr;
  const int k0 = jg * 32 + hi * 8;

  // ---- init: register this block on its real XCD; elect per-XCD leader ----
  unsigned xcc = 0, n_mine = 0, nxa = 0; int is_leader = 0;
  if (tid == 0) {
    xcc = (unsigned)__builtin_amdgcn_s_getreg((31u << 11) | 20u) & 7u;  // HW_REG_XCC_ID
    unsigned myidx = __hip_atomic_fetch_add(bar + B_XTOT(xcc), 1u, __ATOMIC_RELAXED, AGENT);
    is_leader = (myidx == 0u);
    __hip_atomic_fetch_add(bar + B_GCNT0, 1u, __ATOMIC_RELEASE, AGENT);
    while (__hip_atomic_load(bar + B_GCNT0, __ATOMIC_RELAXED, AGENT) < (unsigned)NBLK)
      __builtin_amdgcn_s_sleep(1);
    __builtin_amdgcn_fence(__ATOMIC_ACQUIRE, "agent");
    n_mine = __hip_atomic_load(bar + B_XTOT(xcc), __ATOMIC_RELAXED, AGENT);
    for (int x = 0; x < 8; ++x)
      nxa += (__hip_atomic_load(bar + B_XTOT(x), __ATOMIC_RELAXED, AGENT) > 0u) ? 1u : 0u;
  }

  // one-time: W slice global -> LDS
  {
    const f32x4* src = (const f32x4*)(WT + (size_t)jg * 65536);
    f32x4* dst = (f32x4*)Wlds;
    for (int u = tid; u < 8192; u += NTHR) dst[u] = src[u];
  }
  // h in registers, MFMA C layout
  float h[2][4];
  {
    float a0 = h0[col0], a1 = h0[col0 + 16];
#pragma unroll
    for (int q = 0; q < 4; ++q) { h[0][q] = a0; h[1][q] = a1; }
  }
  float wic[4][2];
#pragma unroll
  for (int i = 0; i < 4; ++i) {
    wic[i][0] = wi_full[i * HDIM + col0];
    wic[i][1] = wi_full[i * HDIM + col0 + 16];
  }
  float woc0[8], woc1[8];
#pragma unroll
  for (int i = 0; i < 8; ++i) {
    woc0[i] = wo_full[k0 + i];
    woc1[i] = wo_full[HDIM + k0 + i];
  }
  __syncthreads();

  // prefetch t=0 noise + input
  float nz[2][4]; float4 xv[4];
#pragma unroll
  for (int q = 0; q < 4; ++q) {
    const int brow = b0w + hi * 4 + q;
    const float* np = noise + ((size_t)brow * TSTEPS + 0) * HDIM;
    nz[0][q] = np[col0];
    nz[1][q] = np[col0 + 16];
    xv[q] = *(const float4*)(inp + ((size_t)brow * TSTEPS + 0) * 4);
  }

  for (int t = 0; t < TSTEPS; ++t) {
    const unsigned short* rr = rbuf + (size_t)(t & 1) * (BATCH * HDIM);
    unsigned short* rw = rbuf + (size_t)((t + 1) & 1) * (BATCH * HDIM);

    // ---- rec = r_t @ wrec.T, 16-deep register-ring A pipeline (cached loads) ----
    const bf16x8* ap = (const bf16x8*)(rr + (size_t)(b0w + lr) * HDIM + hi * 8); // kb stride = 4 (x16B)
    bf16x8 ar[16];
#pragma unroll
    for (int i = 0; i < 16; ++i) ar[i] = ap[i * 4];
    f32x4 acc0 = {0.f, 0.f, 0.f, 0.f}, acc1 = {0.f, 0.f, 0.f, 0.f};
    const bf16x8* Ws = (const bf16x8*)Wlds;
#pragma unroll
    for (int kb = 0; kb < 64; ++kb) {
      bf16x8 a = ar[kb & 15];
      bf16x8 bA = Ws[(kb * 2 + 0) * 64 + l];
      bf16x8 bB = Ws[(kb * 2 + 1) * 64 + l];
      acc0 = __builtin_amdgcn_mfma_f32_16x16x32_bf16(a, bA, acc0, 0, 0, 0);
      acc1 = __builtin_amdgcn_mfma_f32_16x16x32_bf16(a, bB, acc1, 0, 0, 0);
      if (kb < 48) ar[kb & 15] = ap[(kb + 16) * 4];
    }

    // ---- h update + write r_{t+1} (normal cached stores -> land in XCD L2) ----
#pragma unroll
    for (int q = 0; q < 4; ++q) {
      float x0 = xv[q].x * wic[0][0] + xv[q].y * wic[1][0] + xv[q].z * wic[2][0] + xv[q].w * wic[3][0];
      float x1 = xv[q].x * wic[0][1] + xv[q].y * wic[1][1] + xv[q].z * wic[2][1] + xv[q].w * wic[3][1];
      float h0n = 0.8f * h[0][q] + 0.05f * nz[0][q] + 0.2f * (acc0[q] + x0);
      float h1n = 0.8f * h[1][q] + 0.05f * nz[1][q] + 0.2f * (acc1[q] + x1);
      h[0][q] = h0n; h[1][q] = h1n;
      const int brow = b0w + hi * 4 + q;
      unsigned short* rp = rw + (size_t)brow * HDIM;
      rp[col0] = f2bf(tanh_fast(h0n));
      rp[col0 + 16] = f2bf(tanh_fast(h1n));
    }

    // ---- arrive: per-XCD counter; last-on-XCD does the ONE release (wbl2) for this XCD ----
    __syncthreads();  // all waves' stores vmcnt-drained -> in L2
    if (tid == 0) {
      unsigned tk = __hip_atomic_fetch_add(bar + BX_CNT(xcc), 1u, __ATOMIC_RELAXED, AGENT);
      if (tk == (unsigned)(t + 1) * n_mine - 1u) {
        // release: s_waitcnt + buffer_wbl2(sc1) + wait, then the add (1 per XCD per step)
        unsigned g = __hip_atomic_fetch_add(bar + B_GCNT, 1u, __ATOMIC_RELEASE, AGENT);
        if (g == (unsigned)(t + 1) * nxa - 1u)
          __hip_atomic_store(bar + B_GEN, (unsigned)(t + 1), __ATOMIC_RELAXED, AGENT);
      }
    }

    // ---- hidden under barrier: out_t = r_{t+1} @ wo (own rows x own k-slice, same-CU data) ----
    {
      bf16x8 a = *(const bf16x8*)(rw + (size_t)(b0w + lr) * HDIM + k0);
      float o0 = 0.f, o1 = 0.f;
#pragma unroll
      for (int i = 0; i < 8; ++i) {
        float af = (float)a[i];
        o0 += af * woc0[i];
        o1 += af * woc1[i];
      }
      o0 += __shfl_xor(o0, 16, 64); o0 += __shfl_xor(o0, 32, 64);
      o1 += __shfl_xor(o1, 16, 64); o1 += __shfl_xor(o1, 32, 64);
      if (l < 16) {
        float* op = out + (size_t)(b0w + l) * (TSTEPS * 2) + (size_t)t * 2;
        atomicAdd(op, o0);
        atomicAdd(op + 1, o1);
      }
    }

    if (t + 1 < TSTEPS) {
      // ---- hidden under barrier: prefetch t+1 noise + input (immutable lines) ----
#pragma unroll
      for (int q = 0; q < 4; ++q) {
        const int brow = b0w + hi * 4 + q;
        const float* np = noise + ((size_t)brow * TSTEPS + (t + 1)) * HDIM;
        nz[0][q] = np[col0];
        nz[1][q] = np[col0 + 16];
        xv[q] = *(const float4*)(inp + ((size_t)brow * TSTEPS + (t + 1)) * 4);
      }
      // ---- wait: leader invs this XCD's L2 once, posts ready; others wait ready ----
      if (tid == 0) {
        if (is_leader) {
          while (__hip_atomic_load(bar + B_GEN, __ATOMIC_RELAXED, AGENT) < (unsigned)(t + 1))
            __builtin_amdgcn_s_sleep(1);
          __builtin_amdgcn_fence(__ATOMIC_ACQUIRE, "agent");  // buffer_inv sc1: L1+L2 inv
          __hip_atomic_store(bar + BX_RDY(xcc), (unsigned)(t + 1), __ATOMIC_RELAXED, AGENT);
        } else {
          while (__hip_atomic_load(bar + BX_RDY(xcc), __ATOMIC_RELAXED, AGENT) < (unsigned)(t + 1))
            __builtin_amdgcn_s_sleep(1);
        }
      }
      __syncthreads();
      // per-CU L1 invalidate (L2 already inv'd by this XCD's leader); wait for it
      asm volatile("buffer_inv" ::: "memory");
      asm volatile("s_waitcnt vmcnt(0)" ::: "memory");
      __builtin_amdgcn_sched_barrier(0);
    }
  }
}

extern "C" void kernel_launch(void* const* d_in, const int* in_sizes, int n_in,
                              void* d_out, int out_size, void* d_ws, size_t ws_size,
                              hipStream_t stream) {
  const float* inp = (const float*)d_in[0];
  const float* noise = (const float*)d_in[1];
  const float* wi = (const float*)d_in[2];
  const float* si = (const float*)d_in[3];
  const float* m = (const float*)d_in[4];
  const float* n = (const float*)d_in[5];
  const float* rec_noise = (const float*)d_in[6];
  const float* wo = (const float*)d_in[7];
  const float* so = (const float*)d_in[8];
  const float* h0 = (const float*)d_in[9];

  char* ws = (char*)d_ws;
  unsigned short* WT = (unsigned short*)(ws + WT_OFF);
  unsigned short* rbuf = (unsigned short*)(ws + RBUF_OFF);
  float* wi_full = (float*)(ws + WI_OFF);
  float* wo_full = (float*)(ws + WO_OFF);
  unsigned* bar = (unsigned*)(ws + BAR_OFF);
  float* outp = (float*)d_out;

  // rebuild proxy params every call (ws is poisoned before timing)
  prep_wt<<<4096, 256, 0, stream>>>(rec_noise, m, n, WT);
  prep_small<<<2048, 256, 0, stream>>>(wi, si, wo, so, h0, wi_full, wo_full, rbuf);
  hipMemsetAsync(d_out, 0, (size_t)out_size * sizeof(float), stream);
  hipMemsetAsync(bar, 0, 4096, stream);

  hipFuncSetAttribute((const void*)rnn_run, hipFuncAttributeMaxDynamicSharedMemorySize, 131072);
  const unsigned short* WTc = WT;
  void* kargs[9] = {(void*)&inp, (void*)&noise, (void*)&WTc, (void*)&rbuf,
                    (void*)&wi_full, (void*)&wo_full, (void*)&h0, (void*)&outp,
                    (void*)&bar};
  hipLaunchCooperativeKernel((void*)rnn_run, dim3(NBLK), dim3(NTHR), kargs, 131072, stream);
}